// Round 5
// baseline (599.028 us; speedup 1.0000x reference)
//
#include <hip/hip_runtime.h>

#define NN 50000
#define NE 800000
#define NB ((NN + 255) / 256)   // 196 scan blocks

typedef unsigned int uint32;
typedef unsigned short ushort16;

__device__ __forceinline__ ushort16 f2bf(float f) {
    uint32 u = __float_as_uint(f);
    u += 0x7fff + ((u >> 16) & 1);      // round-to-nearest-even
    return (ushort16)(u >> 16);
}
__device__ __forceinline__ float bf_lo(uint32 u) {
    return __uint_as_float(u << 16);
}
__device__ __forceinline__ float bf_hi(uint32 u) {
    return __uint_as_float(u & 0xffff0000u);
}

// ---------------------------------------------------------------------------
// k_lin12: a = x@W1 + b1 ; skip = x@W2 + b2   (x:[NN,128], W:[128,64])
// K chunked by 4: weight chunk in registers (8 independent coalesced loads),
// x-tile read as float4 LDS broadcast -> 64 FMA per 8 LDS b128 + 8 VMEM.
// ---------------------------------------------------------------------------
__global__ __launch_bounds__(256) void k_lin12(
    const float* __restrict__ x,
    const float* __restrict__ w1, const float* __restrict__ b1,
    const float* __restrict__ w2, const float* __restrict__ b2,
    float* __restrict__ a, float* __restrict__ skip)
{
    __shared__ float xs[32][128];
    const int tid = threadIdx.x;
    const int row0 = blockIdx.x * 32;
    for (int i = tid; i < 32 * 128; i += 256) {
        const int gr = row0 + (i >> 7);
        ((float*)xs)[i] = (gr < NN) ? x[gr * 128 + (i & 127)] : 0.f;
    }
    __syncthreads();

    const int col = tid & 63;
    const int g = tid >> 6;
    float acc1[8], acc2[8];
#pragma unroll
    for (int r = 0; r < 8; ++r) { acc1[r] = 0.f; acc2[r] = 0.f; }

#pragma unroll 2
    for (int k0 = 0; k0 < 128; k0 += 4) {
        float wr1[4], wr2[4];
#pragma unroll
        for (int kk = 0; kk < 4; ++kk) {
            wr1[kk] = w1[(k0 + kk) * 64 + col];
            wr2[kk] = w2[(k0 + kk) * 64 + col];
        }
#pragma unroll
        for (int r = 0; r < 8; ++r) {
            const float4 xv = *(const float4*)&xs[g * 8 + r][k0];
            acc1[r] += xv.x * wr1[0] + xv.y * wr1[1] + xv.z * wr1[2] + xv.w * wr1[3];
            acc2[r] += xv.x * wr2[0] + xv.y * wr2[1] + xv.z * wr2[2] + xv.w * wr2[3];
        }
    }

    const float bv1 = b1[col];
    const float bv2 = b2[col];
#pragma unroll
    for (int r = 0; r < 8; ++r) {
        const int gr = row0 + g * 8 + r;
        if (gr < NN) {
            a[gr * 64 + col]    = acc1[r] + bv1;
            skip[gr * 64 + col] = acc2[r] + bv2;
        }
    }
}

// ---------------------------------------------------------------------------
// k_feat: y[node][d][h] = bf16(a@W) head-interleaved, t = a@U per node.
// 16 rows/block; wave g owns rows g*4..g*4+3; each lane owns 4 y-cols
// (lane, lane+64, lane+128, lane+192) -> 4 FMA per broadcast element.
// ---------------------------------------------------------------------------
__global__ __launch_bounds__(256) void k_feat(
    const float* __restrict__ a,
    const float* __restrict__ w, const float* __restrict__ u,
    ushort16* __restrict__ y, float* __restrict__ t)
{
    __shared__ float as[16][64];
    const int tid = threadIdx.x;
    const int row0 = blockIdx.x * 16;
    for (int i = tid; i < 16 * 64; i += 256) {
        const int gr = row0 + (i >> 6);
        ((float*)as)[i] = (gr < NN) ? a[gr * 64 + (i & 63)] : 0.f;
    }
    __syncthreads();

    const int lane = tid & 63;
    const int g = tid >> 6;          // wave -> rows g*4 .. g*4+3

    // W column for y-index c: (c&3)*64 + (c>>2); c = cc*64 + lane
    int wc[4];
#pragma unroll
    for (int cc = 0; cc < 4; ++cc) {
        const int c = cc * 64 + lane;
        wc[cc] = (c & 3) * 64 + (c >> 2);
    }

    float acc[4][4];
#pragma unroll
    for (int r = 0; r < 4; ++r)
#pragma unroll
        for (int cc = 0; cc < 4; ++cc) acc[r][cc] = 0.f;

#pragma unroll 2
    for (int k0 = 0; k0 < 64; k0 += 4) {
        float wr[4][4];
#pragma unroll
        for (int kk = 0; kk < 4; ++kk)
#pragma unroll
            for (int cc = 0; cc < 4; ++cc)
                wr[kk][cc] = w[(k0 + kk) * 256 + wc[cc]];
#pragma unroll
        for (int r = 0; r < 4; ++r) {
            const float4 xv = *(const float4*)&as[g * 4 + r][k0];
#pragma unroll
            for (int cc = 0; cc < 4; ++cc)
                acc[r][cc] += xv.x * wr[0][cc] + xv.y * wr[1][cc]
                            + xv.z * wr[2][cc] + xv.w * wr[3][cc];
        }
    }

#pragma unroll
    for (int r = 0; r < 4; ++r) {
        const int gr = row0 + g * 4 + r;
        if (gr < NN) {
#pragma unroll
            for (int cc = 0; cc < 4; ++cc)
                y[(size_t)gr * 256 + cc * 64 + lane] = f2bf(acc[r][cc]);
        }
    }

    if (tid < 64) {
        const int r = tid >> 2, h = tid & 3;
        float s = 0.f;
        for (int k = 0; k < 64; ++k) s += as[r][k] * u[k * 4 + h];
        const int gr = row0 + r;
        if (gr < NN) t[gr * 4 + h] = s;
    }
}

// ---------------------------------------------------------------------------
// k_lin3: out = h@W + b   ([NN,64]@[64,64]) — same chunked-register pattern
// ---------------------------------------------------------------------------
__global__ __launch_bounds__(256) void k_lin3(
    const float* __restrict__ h,
    const float* __restrict__ w, const float* __restrict__ b,
    float* __restrict__ out)
{
    __shared__ float hs[32][64];
    const int tid = threadIdx.x;
    const int row0 = blockIdx.x * 32;
    for (int i = tid; i < 32 * 64; i += 256) {
        const int gr = row0 + (i >> 6);
        ((float*)hs)[i] = (gr < NN) ? h[gr * 64 + (i & 63)] : 0.f;
    }
    __syncthreads();

    const int col = tid & 63;
    const int g = tid >> 6;
    float acc[8];
#pragma unroll
    for (int r = 0; r < 8; ++r) acc[r] = 0.f;

#pragma unroll 2
    for (int k0 = 0; k0 < 64; k0 += 4) {
        float wr[4];
#pragma unroll
        for (int kk = 0; kk < 4; ++kk)
            wr[kk] = w[(k0 + kk) * 64 + col];
#pragma unroll
        for (int r = 0; r < 8; ++r) {
            const float4 xv = *(const float4*)&hs[g * 8 + r][k0];
            acc[r] += xv.x * wr[0] + xv.y * wr[1] + xv.z * wr[2] + xv.w * wr[3];
        }
    }

    const float bv = b[col];
#pragma unroll
    for (int r = 0; r < 8; ++r) {
        const int gr = row0 + g * 8 + r;
        if (gr < NN) out[gr * 64 + col] = acc[r] + bv;
    }
}

// ---------------------------------------------------------------------------
// CSR build: histogram -> hierarchical scan -> scatter {src,dst} pairs
// ---------------------------------------------------------------------------
__global__ __launch_bounds__(256) void k_hist(const int* __restrict__ ei,
                                              int* __restrict__ deg)
{
    const int i = blockIdx.x * 256 + threadIdx.x;
    if (i < NE) atomicAdd(&deg[ei[NE + i]], 1);
}

__global__ __launch_bounds__(256) void k_blocksum(const int* __restrict__ deg,
                                                  int* __restrict__ bsum)
{
    __shared__ int red[256];
    const int t = threadIdx.x;
    const int i = blockIdx.x * 256 + t;
    red[t] = (i < NN) ? deg[i] : 0;
    __syncthreads();
    for (int off = 128; off > 0; off >>= 1) {
        if (t < off) red[t] += red[t + off];
        __syncthreads();
    }
    if (t == 0) bsum[blockIdx.x] = red[0];
}

__global__ __launch_bounds__(256) void k_scanb(int* __restrict__ bsum)
{
    __shared__ int s[256];
    const int t = threadIdx.x;
    s[t] = (t < NB) ? bsum[t] : 0;
    __syncthreads();
    for (int off = 1; off < 256; off <<= 1) {
        const int v = (t >= off) ? s[t - off] : 0;
        __syncthreads();
        s[t] += v;
        __syncthreads();
    }
    if (t < NB) bsum[t] = (t == 0) ? 0 : s[t - 1];
}

__global__ __launch_bounds__(256) void k_scanfin(const int* __restrict__ deg,
                                                 const int* __restrict__ bsum,
                                                 int* __restrict__ row_ptr,
                                                 int* __restrict__ fill)
{
    __shared__ int s[256];
    const int t = threadIdx.x;
    const int i = blockIdx.x * 256 + t;
    const int v = (i < NN) ? deg[i] : 0;
    s[t] = v;
    __syncthreads();
    for (int off = 1; off < 256; off <<= 1) {
        const int u = (t >= off) ? s[t - off] : 0;
        __syncthreads();
        s[t] += u;
        __syncthreads();
    }
    const int excl = s[t] - v + bsum[blockIdx.x];
    if (i < NN) { row_ptr[i] = excl; fill[i] = excl; }
    if (i == NN - 1) row_ptr[NN] = excl + v;
}

__global__ __launch_bounds__(256) void k_scatter(const int* __restrict__ ei,
                                                 int* __restrict__ fill,
                                                 int2* __restrict__ es)
{
    const int i = blockIdx.x * 256 + threadIdx.x;
    if (i >= NE) return;
    const int src = ei[i];
    const int dst = ei[NE + i];
    const int pos = atomicAdd(&fill[dst], 1);
    es[pos] = make_int2(src, dst);
}

// ---------------------------------------------------------------------------
// k_q: one thread per CSR slot. softmax over heads, pre-scaled by 1/deg,
// packed with src into a 16B record {src, bf16 q0q1, bf16 q2q3, pad}.
// ---------------------------------------------------------------------------
__global__ __launch_bounds__(256) void k_q(
    const int2* __restrict__ es, const float* __restrict__ t,
    const float* __restrict__ c, const int* __restrict__ deg,
    int4* __restrict__ rec)
{
    const int j = blockIdx.x * 256 + threadIdx.x;
    if (j >= NE) return;
    const int2 e = es[j];
    const float4 ts = ((const float4*)t)[e.x];
    const float4 td = ((const float4*)t)[e.y];
    const float4 tc = *(const float4*)c;

    const float l0 = ts.x - td.x + tc.x;
    const float l1 = ts.y - td.y + tc.y;
    const float l2 = ts.z - td.z + tc.z;
    const float l3 = ts.w - td.w + tc.w;
    const float m = fmaxf(fmaxf(l0, l1), fmaxf(l2, l3));
    const float e0 = __expf(l0 - m);
    const float e1 = __expf(l1 - m);
    const float e2 = __expf(l2 - m);
    const float e3 = __expf(l3 - m);
    const float dg = (float)deg[e.y];
    const float s = 1.f / ((e0 + e1 + e2 + e3) * fmaxf(dg, 1.f));

    const uint32 q01 = (uint32)f2bf(e0 * s) | ((uint32)f2bf(e1 * s) << 16);
    const uint32 q23 = (uint32)f2bf(e2 * s) | ((uint32)f2bf(e3 * s) << 16);
    rec[j] = make_int4(e.x, (int)q01, (int)q23, 0);
}

// ---------------------------------------------------------------------------
// k_agg: one wave per dst node, lane = channel. 4-edge unroll: 4 y-gathers
// in flight per wave to cover L2/L3 hit latency. Epilogue fused.
// ---------------------------------------------------------------------------
__global__ __launch_bounds__(256) void k_agg(
    const int* __restrict__ row_ptr, const int4* __restrict__ rec,
    const uint2* __restrict__ y,
    const float* __restrict__ bias, const float* __restrict__ skip,
    float* __restrict__ out)
{
    const int lane = threadIdx.x & 63;
    const int node = (blockIdx.x * 256 + threadIdx.x) >> 6;
    if (node >= NN) return;

    const int r0 = row_ptr[node];
    const int r1 = row_ptr[node + 1];

    float acc = 0.f;
    int j = r0;
    for (; j + 3 < r1; j += 4) {
        const int4 rA = rec[j];
        const int4 rB = rec[j + 1];
        const int4 rC = rec[j + 2];
        const int4 rD = rec[j + 3];
        const uint2 yA = y[(size_t)rA.x * 64 + lane];
        const uint2 yB = y[(size_t)rB.x * 64 + lane];
        const uint2 yC = y[(size_t)rC.x * 64 + lane];
        const uint2 yD = y[(size_t)rD.x * 64 + lane];
        acc += bf_lo((uint32)rA.y) * bf_lo(yA.x) + bf_hi((uint32)rA.y) * bf_hi(yA.x)
             + bf_lo((uint32)rA.z) * bf_lo(yA.y) + bf_hi((uint32)rA.z) * bf_hi(yA.y);
        acc += bf_lo((uint32)rB.y) * bf_lo(yB.x) + bf_hi((uint32)rB.y) * bf_hi(yB.x)
             + bf_lo((uint32)rB.z) * bf_lo(yB.y) + bf_hi((uint32)rB.z) * bf_hi(yB.y);
        acc += bf_lo((uint32)rC.y) * bf_lo(yC.x) + bf_hi((uint32)rC.y) * bf_hi(yC.x)
             + bf_lo((uint32)rC.z) * bf_lo(yC.y) + bf_hi((uint32)rC.z) * bf_hi(yC.y);
        acc += bf_lo((uint32)rD.y) * bf_lo(yD.x) + bf_hi((uint32)rD.y) * bf_hi(yD.x)
             + bf_lo((uint32)rD.z) * bf_lo(yD.y) + bf_hi((uint32)rD.z) * bf_hi(yD.y);
    }
    for (; j < r1; ++j) {
        const int4 rA = rec[j];
        const uint2 yA = y[(size_t)rA.x * 64 + lane];
        acc += bf_lo((uint32)rA.y) * bf_lo(yA.x) + bf_hi((uint32)rA.y) * bf_hi(yA.x)
             + bf_lo((uint32)rA.z) * bf_lo(yA.y) + bf_hi((uint32)rA.z) * bf_hi(yA.y);
    }

    const float v = acc + bias[lane] + skip[node * 64 + lane];
    out[node * 64 + lane] = fmaxf(v, 0.f);
}

extern "C" void kernel_launch(void* const* d_in, const int* in_sizes, int n_in,
                              void* d_out, int out_size, void* d_ws, size_t ws_size,
                              hipStream_t stream) {
    const float* x       = (const float*)d_in[0];
    const int*   ei      = (const int*)d_in[1];   // [2, NE] int32
    const float* lin1_w  = (const float*)d_in[2];
    const float* lin1_b  = (const float*)d_in[3];
    const float* lin2_w  = (const float*)d_in[4];
    const float* lin2_b  = (const float*)d_in[5];
    const float* lin3_w  = (const float*)d_in[6];
    const float* lin3_b  = (const float*)d_in[7];
    const float* conv1_w = (const float*)d_in[8];
    const float* conv1_u = (const float*)d_in[9];
    const float* conv1_c = (const float*)d_in[10];
    const float* conv1_bias = (const float*)d_in[11];
    const float* conv2_w = (const float*)d_in[12];
    const float* conv2_u = (const float*)d_in[13];
    const float* conv2_c = (const float*)d_in[14];
    const float* conv2_bias = (const float*)d_in[15];
    float* out = (float*)d_out;

    // workspace layout (~72 MB, 16B-aligned sections)
    char* p = (char*)d_ws;
    float* a     = (float*)p;            p += (size_t)NN * 64 * 4;
    float* skip  = (float*)p;            p += (size_t)NN * 64 * 4;
    float* tt    = (float*)p;            p += (size_t)NN * 4 * 4;
    ushort16* y  = (ushort16*)p;         p += (size_t)NN * 256 * 2;
    int4* rec    = (int4*)p;             p += (size_t)NE * 16;
    int2* es     = (int2*)p;             p += (size_t)NE * 8;
    int* deg     = (int*)p;              p += (size_t)NN * 4;
    int* row_ptr = (int*)p;              p += (size_t)(NN + 1) * 4;
    int* fill    = (int*)p;              p += (size_t)NN * 4;
    int* bsum    = (int*)p;

    // ---- CSR build (edge_index identical for both layers) ----
    hipMemsetAsync(deg, 0, (size_t)NN * sizeof(int), stream);
    k_hist<<<(NE + 255) / 256, 256, 0, stream>>>(ei, deg);
    k_blocksum<<<NB, 256, 0, stream>>>(deg, bsum);
    k_scanb<<<1, 256, 0, stream>>>(bsum);
    k_scanfin<<<NB, 256, 0, stream>>>(deg, bsum, row_ptr, fill);
    k_scatter<<<(NE + 255) / 256, 256, 0, stream>>>(ei, fill, es);

    // ---- layer 1 ----
    k_lin12<<<(NN + 31) / 32, 256, 0, stream>>>(x, lin1_w, lin1_b, lin2_w, lin2_b, a, skip);
    k_feat<<<(NN + 15) / 16, 256, 0, stream>>>(a, conv1_w, conv1_u, y, tt);
    k_q<<<(NE + 255) / 256, 256, 0, stream>>>(es, tt, conv1_c, deg, rec);
    k_agg<<<(NN + 3) / 4, 256, 0, stream>>>(row_ptr, rec, (const uint2*)y, conv1_bias, skip, a);

    // ---- layer 2 ----
    k_feat<<<(NN + 15) / 16, 256, 0, stream>>>(a, conv2_w, conv2_u, y, tt);
    k_lin3<<<(NN + 31) / 32, 256, 0, stream>>>(a, lin3_w, lin3_b, skip);
    k_q<<<(NE + 255) / 256, 256, 0, stream>>>(es, tt, conv2_c, deg, rec);
    k_agg<<<(NN + 3) / 4, 256, 0, stream>>>(row_ptr, rec, (const uint2*)y, conv2_bias, skip, out);
}

// Round 6
// 492.879 us; speedup vs baseline: 1.2154x; 1.2154x over previous
//
#include <hip/hip_runtime.h>

#define NN 50000
#define NE 800000
#define NB ((NN + 255) / 256)   // 196 scan blocks

typedef unsigned int uint32;
typedef unsigned short ushort16;

__device__ __forceinline__ ushort16 f2bf(float f) {
    uint32 u = __float_as_uint(f);
    u += 0x7fff + ((u >> 16) & 1);      // round-to-nearest-even
    return (ushort16)(u >> 16);
}
__device__ __forceinline__ float bf_lo(uint32 u) {
    return __uint_as_float(u << 16);
}
__device__ __forceinline__ float bf_hi(uint32 u) {
    return __uint_as_float(u & 0xffff0000u);
}

// ---------------------------------------------------------------------------
// k_lin12: a = x@W1 + b1 ; skip = x@W2 + b2   (x:[NN,128], W:[128,64])
// K chunked by 4: weight chunk in registers (8 independent coalesced loads),
// x-tile read as float4 LDS broadcast.
// ---------------------------------------------------------------------------
__global__ __launch_bounds__(256) void k_lin12(
    const float* __restrict__ x,
    const float* __restrict__ w1, const float* __restrict__ b1,
    const float* __restrict__ w2, const float* __restrict__ b2,
    float* __restrict__ a, float* __restrict__ skip)
{
    __shared__ float xs[32][128];
    const int tid = threadIdx.x;
    const int row0 = blockIdx.x * 32;
    for (int i = tid; i < 32 * 128; i += 256) {
        const int gr = row0 + (i >> 7);
        ((float*)xs)[i] = (gr < NN) ? x[gr * 128 + (i & 127)] : 0.f;
    }
    __syncthreads();

    const int col = tid & 63;
    const int g = tid >> 6;
    float acc1[8], acc2[8];
#pragma unroll
    for (int r = 0; r < 8; ++r) { acc1[r] = 0.f; acc2[r] = 0.f; }

#pragma unroll 2
    for (int k0 = 0; k0 < 128; k0 += 4) {
        float wr1[4], wr2[4];
#pragma unroll
        for (int kk = 0; kk < 4; ++kk) {
            wr1[kk] = w1[(k0 + kk) * 64 + col];
            wr2[kk] = w2[(k0 + kk) * 64 + col];
        }
#pragma unroll
        for (int r = 0; r < 8; ++r) {
            const float4 xv = *(const float4*)&xs[g * 8 + r][k0];
            acc1[r] += xv.x * wr1[0] + xv.y * wr1[1] + xv.z * wr1[2] + xv.w * wr1[3];
            acc2[r] += xv.x * wr2[0] + xv.y * wr2[1] + xv.z * wr2[2] + xv.w * wr2[3];
        }
    }

    const float bv1 = b1[col];
    const float bv2 = b2[col];
#pragma unroll
    for (int r = 0; r < 8; ++r) {
        const int gr = row0 + g * 8 + r;
        if (gr < NN) {
            a[gr * 64 + col]    = acc1[r] + bv1;
            skip[gr * 64 + col] = acc2[r] + bv2;
        }
    }
}

// ---------------------------------------------------------------------------
// k_feat: y[node] head-interleaved bf16 = a@W, t = a@U per node.
// R4 mapping (tid = y-col over 256, acc over 16 rows) + K chunked by 4:
// only 4 weight VMEM per chunk; LDS read as wave-uniform float4 broadcast.
// LDS tile padded to 68 floats/row: float4 stays 16B-aligned, and the
// t-loop's as[r][k] (stride-64) becomes 2-way bank aliasing (free) not 16.
// ---------------------------------------------------------------------------
__global__ __launch_bounds__(256) void k_feat(
    const float* __restrict__ a,
    const float* __restrict__ w, const float* __restrict__ u,
    ushort16* __restrict__ y, float* __restrict__ t)
{
    __shared__ float as[16][68];
    const int tid = threadIdx.x;
    const int row0 = blockIdx.x * 16;
    for (int i = tid; i < 16 * 64; i += 256) {
        const int gr = row0 + (i >> 6);
        as[i >> 6][i & 63] = (gr < NN) ? a[gr * 64 + (i & 63)] : 0.f;
    }
    __syncthreads();

    const int wcol = (tid & 3) * 64 + (tid >> 2);  // head-major col in W

    float acc[16];
#pragma unroll
    for (int r = 0; r < 16; ++r) acc[r] = 0.f;

#pragma unroll 2
    for (int k0 = 0; k0 < 64; k0 += 4) {
        float wr[4];
#pragma unroll
        for (int kk = 0; kk < 4; ++kk)
            wr[kk] = w[(k0 + kk) * 256 + wcol];
#pragma unroll
        for (int r = 0; r < 16; ++r) {
            const float4 xv = *(const float4*)&as[r][k0];
            acc[r] += xv.x * wr[0] + xv.y * wr[1] + xv.z * wr[2] + xv.w * wr[3];
        }
    }

#pragma unroll
    for (int r = 0; r < 16; ++r) {
        const int gr = row0 + r;
        if (gr < NN) y[(size_t)gr * 256 + tid] = f2bf(acc[r]);
    }

    if (tid < 64) {
        const int r = tid >> 2, h = tid & 3;
        float s = 0.f;
        for (int k = 0; k < 64; ++k) s += as[r][k] * u[k * 4 + h];
        const int gr = row0 + r;
        if (gr < NN) t[gr * 4 + h] = s;
    }
}

// ---------------------------------------------------------------------------
// k_lin3: out = h@W + b   ([NN,64]@[64,64]) — chunked-register pattern
// ---------------------------------------------------------------------------
__global__ __launch_bounds__(256) void k_lin3(
    const float* __restrict__ h,
    const float* __restrict__ w, const float* __restrict__ b,
    float* __restrict__ out)
{
    __shared__ float hs[32][64];
    const int tid = threadIdx.x;
    const int row0 = blockIdx.x * 32;
    for (int i = tid; i < 32 * 64; i += 256) {
        const int gr = row0 + (i >> 6);
        ((float*)hs)[i] = (gr < NN) ? h[gr * 64 + (i & 63)] : 0.f;
    }
    __syncthreads();

    const int col = tid & 63;
    const int g = tid >> 6;
    float acc[8];
#pragma unroll
    for (int r = 0; r < 8; ++r) acc[r] = 0.f;

#pragma unroll 2
    for (int k0 = 0; k0 < 64; k0 += 4) {
        float wr[4];
#pragma unroll
        for (int kk = 0; kk < 4; ++kk)
            wr[kk] = w[(k0 + kk) * 64 + col];
#pragma unroll
        for (int r = 0; r < 8; ++r) {
            const float4 xv = *(const float4*)&hs[g * 8 + r][k0];
            acc[r] += xv.x * wr[0] + xv.y * wr[1] + xv.z * wr[2] + xv.w * wr[3];
        }
    }

    const float bv = b[col];
#pragma unroll
    for (int r = 0; r < 8; ++r) {
        const int gr = row0 + g * 8 + r;
        if (gr < NN) out[gr * 64 + col] = acc[r] + bv;
    }
}

// ---------------------------------------------------------------------------
// CSR build: histogram -> hierarchical scan -> scatter {src,dst} pairs
// ---------------------------------------------------------------------------
__global__ __launch_bounds__(256) void k_hist(const int* __restrict__ ei,
                                              int* __restrict__ deg)
{
    const int i = blockIdx.x * 256 + threadIdx.x;
    if (i < NE) atomicAdd(&deg[ei[NE + i]], 1);
}

__global__ __launch_bounds__(256) void k_blocksum(const int* __restrict__ deg,
                                                  int* __restrict__ bsum)
{
    __shared__ int red[256];
    const int t = threadIdx.x;
    const int i = blockIdx.x * 256 + t;
    red[t] = (i < NN) ? deg[i] : 0;
    __syncthreads();
    for (int off = 128; off > 0; off >>= 1) {
        if (t < off) red[t] += red[t + off];
        __syncthreads();
    }
    if (t == 0) bsum[blockIdx.x] = red[0];
}

__global__ __launch_bounds__(256) void k_scanb(int* __restrict__ bsum)
{
    __shared__ int s[256];
    const int t = threadIdx.x;
    s[t] = (t < NB) ? bsum[t] : 0;
    __syncthreads();
    for (int off = 1; off < 256; off <<= 1) {
        const int v = (t >= off) ? s[t - off] : 0;
        __syncthreads();
        s[t] += v;
        __syncthreads();
    }
    if (t < NB) bsum[t] = (t == 0) ? 0 : s[t - 1];
}

__global__ __launch_bounds__(256) void k_scanfin(const int* __restrict__ deg,
                                                 const int* __restrict__ bsum,
                                                 int* __restrict__ row_ptr,
                                                 int* __restrict__ fill)
{
    __shared__ int s[256];
    const int t = threadIdx.x;
    const int i = blockIdx.x * 256 + t;
    const int v = (i < NN) ? deg[i] : 0;
    s[t] = v;
    __syncthreads();
    for (int off = 1; off < 256; off <<= 1) {
        const int u = (t >= off) ? s[t - off] : 0;
        __syncthreads();
        s[t] += u;
        __syncthreads();
    }
    const int excl = s[t] - v + bsum[blockIdx.x];
    if (i < NN) { row_ptr[i] = excl; fill[i] = excl; }
    if (i == NN - 1) row_ptr[NN] = excl + v;
}

__global__ __launch_bounds__(256) void k_scatter(const int* __restrict__ ei,
                                                 int* __restrict__ fill,
                                                 int2* __restrict__ es)
{
    const int i = blockIdx.x * 256 + threadIdx.x;
    if (i >= NE) return;
    const int src = ei[i];
    const int dst = ei[NE + i];
    const int pos = atomicAdd(&fill[dst], 1);
    es[pos] = make_int2(src, dst);
}

// ---------------------------------------------------------------------------
// k_q: one thread per CSR slot. softmax over heads, pre-scaled by 1/deg,
// packed with src into a 16B record {src, bf16 q0q1, bf16 q2q3, pad}.
// ---------------------------------------------------------------------------
__global__ __launch_bounds__(256) void k_q(
    const int2* __restrict__ es, const float* __restrict__ t,
    const float* __restrict__ c, const int* __restrict__ deg,
    int4* __restrict__ rec)
{
    const int j = blockIdx.x * 256 + threadIdx.x;
    if (j >= NE) return;
    const int2 e = es[j];
    const float4 ts = ((const float4*)t)[e.x];
    const float4 td = ((const float4*)t)[e.y];
    const float4 tc = *(const float4*)c;

    const float l0 = ts.x - td.x + tc.x;
    const float l1 = ts.y - td.y + tc.y;
    const float l2 = ts.z - td.z + tc.z;
    const float l3 = ts.w - td.w + tc.w;
    const float m = fmaxf(fmaxf(l0, l1), fmaxf(l2, l3));
    const float e0 = __expf(l0 - m);
    const float e1 = __expf(l1 - m);
    const float e2 = __expf(l2 - m);
    const float e3 = __expf(l3 - m);
    const float dg = (float)deg[e.y];
    const float s = 1.f / ((e0 + e1 + e2 + e3) * fmaxf(dg, 1.f));

    const uint32 q01 = (uint32)f2bf(e0 * s) | ((uint32)f2bf(e1 * s) << 16);
    const uint32 q23 = (uint32)f2bf(e2 * s) | ((uint32)f2bf(e3 * s) << 16);
    rec[j] = make_int4(e.x, (int)q01, (int)q23, 0);
}

// ---------------------------------------------------------------------------
// k_agg: one wave per dst node, lane = channel. 4-edge unroll: 4 y-gathers
// in flight per wave to cover L2/L3 hit latency. Epilogue fused.
// ---------------------------------------------------------------------------
__global__ __launch_bounds__(256) void k_agg(
    const int* __restrict__ row_ptr, const int4* __restrict__ rec,
    const uint2* __restrict__ y,
    const float* __restrict__ bias, const float* __restrict__ skip,
    float* __restrict__ out)
{
    const int lane = threadIdx.x & 63;
    const int node = (blockIdx.x * 256 + threadIdx.x) >> 6;
    if (node >= NN) return;

    const int r0 = row_ptr[node];
    const int r1 = row_ptr[node + 1];

    float acc = 0.f;
    int j = r0;
    for (; j + 3 < r1; j += 4) {
        const int4 rA = rec[j];
        const int4 rB = rec[j + 1];
        const int4 rC = rec[j + 2];
        const int4 rD = rec[j + 3];
        const uint2 yA = y[(size_t)rA.x * 64 + lane];
        const uint2 yB = y[(size_t)rB.x * 64 + lane];
        const uint2 yC = y[(size_t)rC.x * 64 + lane];
        const uint2 yD = y[(size_t)rD.x * 64 + lane];
        acc += bf_lo((uint32)rA.y) * bf_lo(yA.x) + bf_hi((uint32)rA.y) * bf_hi(yA.x)
             + bf_lo((uint32)rA.z) * bf_lo(yA.y) + bf_hi((uint32)rA.z) * bf_hi(yA.y);
        acc += bf_lo((uint32)rB.y) * bf_lo(yB.x) + bf_hi((uint32)rB.y) * bf_hi(yB.x)
             + bf_lo((uint32)rB.z) * bf_lo(yB.y) + bf_hi((uint32)rB.z) * bf_hi(yB.y);
        acc += bf_lo((uint32)rC.y) * bf_lo(yC.x) + bf_hi((uint32)rC.y) * bf_hi(yC.x)
             + bf_lo((uint32)rC.z) * bf_lo(yC.y) + bf_hi((uint32)rC.z) * bf_hi(yC.y);
        acc += bf_lo((uint32)rD.y) * bf_lo(yD.x) + bf_hi((uint32)rD.y) * bf_hi(yD.x)
             + bf_lo((uint32)rD.z) * bf_lo(yD.y) + bf_hi((uint32)rD.z) * bf_hi(yD.y);
    }
    for (; j < r1; ++j) {
        const int4 rA = rec[j];
        const uint2 yA = y[(size_t)rA.x * 64 + lane];
        acc += bf_lo((uint32)rA.y) * bf_lo(yA.x) + bf_hi((uint32)rA.y) * bf_hi(yA.x)
             + bf_lo((uint32)rA.z) * bf_lo(yA.y) + bf_hi((uint32)rA.z) * bf_hi(yA.y);
    }

    const float v = acc + bias[lane] + skip[node * 64 + lane];
    out[node * 64 + lane] = fmaxf(v, 0.f);
}

extern "C" void kernel_launch(void* const* d_in, const int* in_sizes, int n_in,
                              void* d_out, int out_size, void* d_ws, size_t ws_size,
                              hipStream_t stream) {
    const float* x       = (const float*)d_in[0];
    const int*   ei      = (const int*)d_in[1];   // [2, NE] int32
    const float* lin1_w  = (const float*)d_in[2];
    const float* lin1_b  = (const float*)d_in[3];
    const float* lin2_w  = (const float*)d_in[4];
    const float* lin2_b  = (const float*)d_in[5];
    const float* lin3_w  = (const float*)d_in[6];
    const float* lin3_b  = (const float*)d_in[7];
    const float* conv1_w = (const float*)d_in[8];
    const float* conv1_u = (const float*)d_in[9];
    const float* conv1_c = (const float*)d_in[10];
    const float* conv1_bias = (const float*)d_in[11];
    const float* conv2_w = (const float*)d_in[12];
    const float* conv2_u = (const float*)d_in[13];
    const float* conv2_c = (const float*)d_in[14];
    const float* conv2_bias = (const float*)d_in[15];
    float* out = (float*)d_out;

    // workspace layout (~72 MB, 16B-aligned sections)
    char* p = (char*)d_ws;
    float* a     = (float*)p;            p += (size_t)NN * 64 * 4;
    float* skip  = (float*)p;            p += (size_t)NN * 64 * 4;
    float* tt    = (float*)p;            p += (size_t)NN * 4 * 4;
    ushort16* y  = (ushort16*)p;         p += (size_t)NN * 256 * 2;
    int4* rec    = (int4*)p;             p += (size_t)NE * 16;
    int2* es     = (int2*)p;             p += (size_t)NE * 8;
    int* deg     = (int*)p;              p += (size_t)NN * 4;
    int* row_ptr = (int*)p;              p += (size_t)(NN + 1) * 4;
    int* fill    = (int*)p;              p += (size_t)NN * 4;
    int* bsum    = (int*)p;

    // ---- CSR build (edge_index identical for both layers) ----
    hipMemsetAsync(deg, 0, (size_t)NN * sizeof(int), stream);
    k_hist<<<(NE + 255) / 256, 256, 0, stream>>>(ei, deg);
    k_blocksum<<<NB, 256, 0, stream>>>(deg, bsum);
    k_scanb<<<1, 256, 0, stream>>>(bsum);
    k_scanfin<<<NB, 256, 0, stream>>>(deg, bsum, row_ptr, fill);
    k_scatter<<<(NE + 255) / 256, 256, 0, stream>>>(ei, fill, es);

    // ---- layer 1 ----
    k_lin12<<<(NN + 31) / 32, 256, 0, stream>>>(x, lin1_w, lin1_b, lin2_w, lin2_b, a, skip);
    k_feat<<<(NN + 15) / 16, 256, 0, stream>>>(a, conv1_w, conv1_u, y, tt);
    k_q<<<(NE + 255) / 256, 256, 0, stream>>>(es, tt, conv1_c, deg, rec);
    k_agg<<<(NN + 3) / 4, 256, 0, stream>>>(row_ptr, rec, (const uint2*)y, conv1_bias, skip, a);

    // ---- layer 2 ----
    k_feat<<<(NN + 15) / 16, 256, 0, stream>>>(a, conv2_w, conv2_u, y, tt);
    k_lin3<<<(NN + 31) / 32, 256, 0, stream>>>(a, lin3_w, lin3_b, skip);
    k_q<<<(NE + 255) / 256, 256, 0, stream>>>(es, tt, conv2_c, deg, rec);
    k_agg<<<(NN + 3) / 4, 256, 0, stream>>>(row_ptr, rec, (const uint2*)y, conv2_bias, skip, out);
}

// Round 7
// 468.822 us; speedup vs baseline: 1.2777x; 1.0513x over previous
//
#include <hip/hip_runtime.h>

#define NN 50000
#define NE 800000
#define NB ((NN + 255) / 256)   // 196 scan blocks

typedef unsigned int uint32;
typedef unsigned short ushort16;

__device__ __forceinline__ ushort16 f2bf(float f) {
    uint32 u = __float_as_uint(f);
    u += 0x7fff + ((u >> 16) & 1);      // round-to-nearest-even
    return (ushort16)(u >> 16);
}
__device__ __forceinline__ float bf_lo(uint32 u) {
    return __uint_as_float(u << 16);
}
__device__ __forceinline__ float bf_hi(uint32 u) {
    return __uint_as_float(u & 0xffff0000u);
}

// ---------------------------------------------------------------------------
// k_lin12: a = x@W1 + b1 ; skip = x@W2 + b2   (x:[NN,128], W:[128,64])
// ---------------------------------------------------------------------------
__global__ __launch_bounds__(256) void k_lin12(
    const float* __restrict__ x,
    const float* __restrict__ w1, const float* __restrict__ b1,
    const float* __restrict__ w2, const float* __restrict__ b2,
    float* __restrict__ a, float* __restrict__ skip)
{
    __shared__ float xs[32][128];
    const int tid = threadIdx.x;
    const int row0 = blockIdx.x * 32;
    for (int i = tid; i < 32 * 128; i += 256) {
        const int gr = row0 + (i >> 7);
        ((float*)xs)[i] = (gr < NN) ? x[gr * 128 + (i & 127)] : 0.f;
    }
    __syncthreads();

    const int col = tid & 63;
    const int g = tid >> 6;
    float acc1[8], acc2[8];
#pragma unroll
    for (int r = 0; r < 8; ++r) { acc1[r] = 0.f; acc2[r] = 0.f; }

#pragma unroll 2
    for (int k0 = 0; k0 < 128; k0 += 4) {
        float wr1[4], wr2[4];
#pragma unroll
        for (int kk = 0; kk < 4; ++kk) {
            wr1[kk] = w1[(k0 + kk) * 64 + col];
            wr2[kk] = w2[(k0 + kk) * 64 + col];
        }
#pragma unroll
        for (int r = 0; r < 8; ++r) {
            const float4 xv = *(const float4*)&xs[g * 8 + r][k0];
            acc1[r] += xv.x * wr1[0] + xv.y * wr1[1] + xv.z * wr1[2] + xv.w * wr1[3];
            acc2[r] += xv.x * wr2[0] + xv.y * wr2[1] + xv.z * wr2[2] + xv.w * wr2[3];
        }
    }

    const float bv1 = b1[col];
    const float bv2 = b2[col];
#pragma unroll
    for (int r = 0; r < 8; ++r) {
        const int gr = row0 + g * 8 + r;
        if (gr < NN) {
            a[gr * 64 + col]    = acc1[r] + bv1;
            skip[gr * 64 + col] = acc2[r] + bv2;
        }
    }
}

// ---------------------------------------------------------------------------
// k_feat: y[node] head-interleaved bf16 = a@W, t = a@U per node.
// LDS tile padded to 68 floats/row (16B-aligned float4 reads; t-loop's
// stride-64 becomes free 2-way bank aliasing).
// ---------------------------------------------------------------------------
__global__ __launch_bounds__(256) void k_feat(
    const float* __restrict__ a,
    const float* __restrict__ w, const float* __restrict__ u,
    ushort16* __restrict__ y, float* __restrict__ t)
{
    __shared__ float as[16][68];
    const int tid = threadIdx.x;
    const int row0 = blockIdx.x * 16;
    for (int i = tid; i < 16 * 64; i += 256) {
        const int gr = row0 + (i >> 6);
        as[i >> 6][i & 63] = (gr < NN) ? a[gr * 64 + (i & 63)] : 0.f;
    }
    __syncthreads();

    const int wcol = (tid & 3) * 64 + (tid >> 2);  // head-major col in W

    float acc[16];
#pragma unroll
    for (int r = 0; r < 16; ++r) acc[r] = 0.f;

#pragma unroll 2
    for (int k0 = 0; k0 < 64; k0 += 4) {
        float wr[4];
#pragma unroll
        for (int kk = 0; kk < 4; ++kk)
            wr[kk] = w[(k0 + kk) * 256 + wcol];
#pragma unroll
        for (int r = 0; r < 16; ++r) {
            const float4 xv = *(const float4*)&as[r][k0];
            acc[r] += xv.x * wr[0] + xv.y * wr[1] + xv.z * wr[2] + xv.w * wr[3];
        }
    }

#pragma unroll
    for (int r = 0; r < 16; ++r) {
        const int gr = row0 + r;
        if (gr < NN) y[(size_t)gr * 256 + tid] = f2bf(acc[r]);
    }

    if (tid < 64) {
        const int r = tid >> 2, h = tid & 3;
        float s = 0.f;
        for (int k = 0; k < 64; ++k) s += as[r][k] * u[k * 4 + h];
        const int gr = row0 + r;
        if (gr < NN) t[gr * 4 + h] = s;
    }
}

// ---------------------------------------------------------------------------
// k_lin3: out = h@W + b   ([NN,64]@[64,64])
// ---------------------------------------------------------------------------
__global__ __launch_bounds__(256) void k_lin3(
    const float* __restrict__ h,
    const float* __restrict__ w, const float* __restrict__ b,
    float* __restrict__ out)
{
    __shared__ float hs[32][64];
    const int tid = threadIdx.x;
    const int row0 = blockIdx.x * 32;
    for (int i = tid; i < 32 * 64; i += 256) {
        const int gr = row0 + (i >> 6);
        ((float*)hs)[i] = (gr < NN) ? h[gr * 64 + (i & 63)] : 0.f;
    }
    __syncthreads();

    const int col = tid & 63;
    const int g = tid >> 6;
    float acc[8];
#pragma unroll
    for (int r = 0; r < 8; ++r) acc[r] = 0.f;

#pragma unroll 2
    for (int k0 = 0; k0 < 64; k0 += 4) {
        float wr[4];
#pragma unroll
        for (int kk = 0; kk < 4; ++kk)
            wr[kk] = w[(k0 + kk) * 64 + col];
#pragma unroll
        for (int r = 0; r < 8; ++r) {
            const float4 xv = *(const float4*)&hs[g * 8 + r][k0];
            acc[r] += xv.x * wr[0] + xv.y * wr[1] + xv.z * wr[2] + xv.w * wr[3];
        }
    }

    const float bv = b[col];
#pragma unroll
    for (int r = 0; r < 8; ++r) {
        const int gr = row0 + g * 8 + r;
        if (gr < NN) out[gr * 64 + col] = acc[r] + bv;
    }
}

// ---------------------------------------------------------------------------
// CSR build: histogram -> hierarchical scan -> scatter (src only, 4B)
// ---------------------------------------------------------------------------
__global__ __launch_bounds__(256) void k_hist(const int* __restrict__ ei,
                                              int* __restrict__ deg)
{
    const int i = blockIdx.x * 256 + threadIdx.x;
    if (i < NE) atomicAdd(&deg[ei[NE + i]], 1);
}

__global__ __launch_bounds__(256) void k_blocksum(const int* __restrict__ deg,
                                                  int* __restrict__ bsum)
{
    __shared__ int red[256];
    const int t = threadIdx.x;
    const int i = blockIdx.x * 256 + t;
    red[t] = (i < NN) ? deg[i] : 0;
    __syncthreads();
    for (int off = 128; off > 0; off >>= 1) {
        if (t < off) red[t] += red[t + off];
        __syncthreads();
    }
    if (t == 0) bsum[blockIdx.x] = red[0];
}

__global__ __launch_bounds__(256) void k_scanb(int* __restrict__ bsum)
{
    __shared__ int s[256];
    const int t = threadIdx.x;
    s[t] = (t < NB) ? bsum[t] : 0;
    __syncthreads();
    for (int off = 1; off < 256; off <<= 1) {
        const int v = (t >= off) ? s[t - off] : 0;
        __syncthreads();
        s[t] += v;
        __syncthreads();
    }
    if (t < NB) bsum[t] = (t == 0) ? 0 : s[t - 1];
}

__global__ __launch_bounds__(256) void k_scanfin(const int* __restrict__ deg,
                                                 const int* __restrict__ bsum,
                                                 int* __restrict__ row_ptr,
                                                 int* __restrict__ fill)
{
    __shared__ int s[256];
    const int t = threadIdx.x;
    const int i = blockIdx.x * 256 + t;
    const int v = (i < NN) ? deg[i] : 0;
    s[t] = v;
    __syncthreads();
    for (int off = 1; off < 256; off <<= 1) {
        const int u = (t >= off) ? s[t - off] : 0;
        __syncthreads();
        s[t] += u;
        __syncthreads();
    }
    const int excl = s[t] - v + bsum[blockIdx.x];
    if (i < NN) { row_ptr[i] = excl; fill[i] = excl; }
    if (i == NN - 1) row_ptr[NN] = excl + v;
}

__global__ __launch_bounds__(256) void k_scatter(const int* __restrict__ ei,
                                                 int* __restrict__ fill,
                                                 int* __restrict__ ssrc)
{
    const int i = blockIdx.x * 256 + threadIdx.x;
    if (i >= NE) return;
    const int src = ei[i];
    const int dst = ei[NE + i];
    const int pos = atomicAdd(&fill[dst], 1);
    ssrc[pos] = src;   // 4B random store (half the line-dup write-back of 8B)
}

// ---------------------------------------------------------------------------
// k_agg: one wave per dst node, lane = channel. Fused softmax:
// per 64-edge chunk, lane i computes edge i's softmax q (coalesced ssrc read,
// up to 64 t-gathers in flight), then the accumulation loop broadcasts
// q/src via __shfl (uniform index) and gathers y coalesced per row.
// Epilogue mean+bias+skip+relu fused. No atomics, no rec/es arrays.
// ---------------------------------------------------------------------------
__global__ __launch_bounds__(256) void k_agg(
    const int* __restrict__ row_ptr, const int* __restrict__ ssrc,
    const float* __restrict__ t, const uint2* __restrict__ y,
    const float* __restrict__ c,
    const float* __restrict__ bias, const float* __restrict__ skip,
    float* __restrict__ out)
{
    const int lane = threadIdx.x & 63;
    const int node = (blockIdx.x * 256 + threadIdx.x) >> 6;
    if (node >= NN) return;

    const int r0 = row_ptr[node];
    const int r1 = row_ptr[node + 1];
    const int deg = r1 - r0;
    const float invdeg = (deg > 0) ? 1.f / (float)deg : 0.f;

    const float4 tc = *(const float4*)c;
    const float4 td = ((const float4*)t)[node];

    float acc = 0.f;
    for (int base = r0; base < r1; base += 64) {
        const int m = min(64, r1 - base);

        // --- phase 1: lane i computes softmax for edge base+i ---
        int src = 0;
        float q0 = 0.f, q1 = 0.f, q2 = 0.f, q3 = 0.f;
        if (lane < m) {
            src = ssrc[base + lane];
            const float4 ts = ((const float4*)t)[src];
            const float l0 = ts.x - td.x + tc.x;
            const float l1 = ts.y - td.y + tc.y;
            const float l2 = ts.z - td.z + tc.z;
            const float l3 = ts.w - td.w + tc.w;
            const float mx = fmaxf(fmaxf(l0, l1), fmaxf(l2, l3));
            const float e0 = __expf(l0 - mx);
            const float e1 = __expf(l1 - mx);
            const float e2 = __expf(l2 - mx);
            const float e3 = __expf(l3 - mx);
            const float s = invdeg / (e0 + e1 + e2 + e3);
            q0 = e0 * s; q1 = e1 * s; q2 = e2 * s; q3 = e3 * s;
        }

        // --- phase 2: accumulate, broadcasting per-edge q/src via shfl ---
        int e = 0;
        for (; e + 3 < m; e += 4) {
#pragma unroll
            for (int k = 0; k < 4; ++k) {
                const int se = __shfl(src, e + k, 64);
                const float a0 = __shfl(q0, e + k, 64);
                const float a1 = __shfl(q1, e + k, 64);
                const float a2 = __shfl(q2, e + k, 64);
                const float a3 = __shfl(q3, e + k, 64);
                const uint2 yv = y[(size_t)se * 64 + lane];
                acc += a0 * bf_lo(yv.x) + a1 * bf_hi(yv.x)
                     + a2 * bf_lo(yv.y) + a3 * bf_hi(yv.y);
            }
        }
        for (; e < m; ++e) {
            const int se = __shfl(src, e, 64);
            const float a0 = __shfl(q0, e, 64);
            const float a1 = __shfl(q1, e, 64);
            const float a2 = __shfl(q2, e, 64);
            const float a3 = __shfl(q3, e, 64);
            const uint2 yv = y[(size_t)se * 64 + lane];
            acc += a0 * bf_lo(yv.x) + a1 * bf_hi(yv.x)
                 + a2 * bf_lo(yv.y) + a3 * bf_hi(yv.y);
        }
    }

    const float v = acc + bias[lane] + skip[node * 64 + lane];
    out[node * 64 + lane] = fmaxf(v, 0.f);
}

extern "C" void kernel_launch(void* const* d_in, const int* in_sizes, int n_in,
                              void* d_out, int out_size, void* d_ws, size_t ws_size,
                              hipStream_t stream) {
    const float* x       = (const float*)d_in[0];
    const int*   ei      = (const int*)d_in[1];   // [2, NE] int32
    const float* lin1_w  = (const float*)d_in[2];
    const float* lin1_b  = (const float*)d_in[3];
    const float* lin2_w  = (const float*)d_in[4];
    const float* lin2_b  = (const float*)d_in[5];
    const float* lin3_w  = (const float*)d_in[6];
    const float* lin3_b  = (const float*)d_in[7];
    const float* conv1_w = (const float*)d_in[8];
    const float* conv1_u = (const float*)d_in[9];
    const float* conv1_c = (const float*)d_in[10];
    const float* conv1_bias = (const float*)d_in[11];
    const float* conv2_w = (const float*)d_in[12];
    const float* conv2_u = (const float*)d_in[13];
    const float* conv2_c = (const float*)d_in[14];
    const float* conv2_bias = (const float*)d_in[15];
    float* out = (float*)d_out;

    // workspace layout (~57 MB, 16B-aligned sections)
    char* p = (char*)d_ws;
    float* a     = (float*)p;            p += (size_t)NN * 64 * 4;
    float* skip  = (float*)p;            p += (size_t)NN * 64 * 4;
    float* tt    = (float*)p;            p += (size_t)NN * 4 * 4;
    ushort16* y  = (ushort16*)p;         p += (size_t)NN * 256 * 2;
    int* ssrc    = (int*)p;              p += (size_t)NE * 4;
    int* deg     = (int*)p;              p += (size_t)NN * 4;
    int* row_ptr = (int*)p;              p += (size_t)(NN + 1) * 4;
    int* fill    = (int*)p;              p += (size_t)NN * 4;
    int* bsum    = (int*)p;

    // ---- CSR build (edge_index identical for both layers) ----
    hipMemsetAsync(deg, 0, (size_t)NN * sizeof(int), stream);
    k_hist<<<(NE + 255) / 256, 256, 0, stream>>>(ei, deg);
    k_blocksum<<<NB, 256, 0, stream>>>(deg, bsum);
    k_scanb<<<1, 256, 0, stream>>>(bsum);
    k_scanfin<<<NB, 256, 0, stream>>>(deg, bsum, row_ptr, fill);
    k_scatter<<<(NE + 255) / 256, 256, 0, stream>>>(ei, fill, ssrc);

    // ---- layer 1 ----
    k_lin12<<<(NN + 31) / 32, 256, 0, stream>>>(x, lin1_w, lin1_b, lin2_w, lin2_b, a, skip);
    k_feat<<<(NN + 15) / 16, 256, 0, stream>>>(a, conv1_w, conv1_u, y, tt);
    k_agg<<<(NN + 3) / 4, 256, 0, stream>>>(row_ptr, ssrc, tt, (const uint2*)y,
                                            conv1_c, conv1_bias, skip, a);

    // ---- layer 2 ----
    k_feat<<<(NN + 15) / 16, 256, 0, stream>>>(a, conv2_w, conv2_u, y, tt);
    k_lin3<<<(NN + 31) / 32, 256, 0, stream>>>(a, lin3_w, lin3_b, skip);
    k_agg<<<(NN + 3) / 4, 256, 0, stream>>>(row_ptr, ssrc, tt, (const uint2*)y,
                                            conv2_c, conv2_bias, skip, out);
}